// Round 5
// baseline (323.067 us; speedup 1.0000x reference)
//
#include <hip/hip_runtime.h>
#include <hip/hip_bf16.h>
#include <cstdint>
#include <cstddef>

#define B_   4
#define T_   4096
#define C_   1024
#define H_   16
#define NC_  64
#define M_   (B_*T_)     // 16384 rows
#define N3_  (3*C_)      // 3072

typedef __attribute__((ext_vector_type(4))) float  f32x4;
typedef __attribute__((ext_vector_type(8))) __bf16 bf16x8;
typedef __attribute__((ext_vector_type(4))) __bf16 bf16x4;
typedef __attribute__((ext_vector_type(8))) unsigned short u16x8;

__device__ __forceinline__ void glds16(void* lds, const void* g) {
  __builtin_amdgcn_global_load_lds((const __attribute__((address_space(1))) void*)g,
                                   (__attribute__((address_space(3))) void*)lds,
                                   16, 0, 0);
}

// ---------------- fp32 -> bf16 ----------------
__global__ __launch_bounds__(256) void cvt_f32_bf16(const float* __restrict__ in,
                                                    __bf16* __restrict__ out, int n4) {
  int i = blockIdx.x * 256 + threadIdx.x;
  if (i >= n4) return;
  float4 v = reinterpret_cast<const float4*>(in)[i];
  bf16x4 o;
  o[0] = (__bf16)v.x; o[1] = (__bf16)v.y; o[2] = (__bf16)v.z; o[3] = (__bf16)v.w;
  reinterpret_cast<bf16x4*>(out)[i] = o;
}

// ---------------- GEMM: C[M][N] = A[M][K] * Bt[N][K]^T  (m97-style 128x128 tile) ----------------
// OUTF==0: bf16 output, OUTF==1: fp32 output
template<int OUTF>
__global__ __launch_bounds__(256) void gemm_bt(const __bf16* __restrict__ A,
                                               const __bf16* __restrict__ Bt,
                                               void* __restrict__ Cout,
                                               int M, int N, int K) {
  __shared__ __bf16 sA[128 * 32];   // [row][k], 64B rows
  __shared__ __bf16 sB[128 * 32];
  const int tid  = threadIdx.x;
  const int lane = tid & 63;
  const int wave = tid >> 6;
  const int wr = wave >> 1, wc = wave & 1;           // 2x2 waves, each 64x64
  const int bm = blockIdx.y, bn = blockIdx.x;

  // staging: per wave 2 x 1KB segments per tile; lane covers row=seg+lane/4, col8=lane%4
  const int srow = wave * 32 + (lane >> 2);
  const int scol = (lane & 3) * 8;
  const __bf16* Ag = A  + (size_t)(bm * 128 + srow) * K + scol;
  const __bf16* Bg = Bt + (size_t)(bn * 128 + srow) * K + scol;
  __bf16* lA0 = sA + wave * 1024 + lane * 8;
  __bf16* lA1 = lA0 + 512;
  __bf16* lB0 = sB + wave * 1024 + lane * 8;
  __bf16* lB1 = lB0 + 512;

  f32x4 acc[4][4];
#pragma unroll
  for (int i = 0; i < 4; i++)
#pragma unroll
    for (int j = 0; j < 4; j++) acc[i][j] = (f32x4)0.0f;

  const int fr = lane & 15;
  const int kb = (lane >> 4) * 8;

  for (int kt = 0; kt < K; kt += 32) {
    __syncthreads();
    glds16(lA0, Ag + kt);
    glds16(lA1, Ag + (size_t)16 * K + kt);
    glds16(lB0, Bg + kt);
    glds16(lB1, Bg + (size_t)16 * K + kt);
    __syncthreads();
    bf16x8 af[4], bfr[4];
#pragma unroll
    for (int i = 0; i < 4; i++)
      af[i] = *(const bf16x8*)(sA + (wr * 64 + i * 16 + fr) * 32 + kb);
#pragma unroll
    for (int j = 0; j < 4; j++)
      bfr[j] = *(const bf16x8*)(sB + (wc * 64 + j * 16 + fr) * 32 + kb);
#pragma unroll
    for (int i = 0; i < 4; i++)
#pragma unroll
      for (int j = 0; j < 4; j++)
        acc[i][j] = __builtin_amdgcn_mfma_f32_16x16x32_bf16(af[i], bfr[j], acc[i][j], 0, 0, 0);
  }

  const int rg = (lane >> 4) * 4;
#pragma unroll
  for (int i = 0; i < 4; i++) {
#pragma unroll
    for (int j = 0; j < 4; j++) {
      size_t row = (size_t)bm * 128 + wr * 64 + i * 16 + rg;
      size_t col = (size_t)bn * 128 + wc * 64 + j * 16 + fr;
#pragma unroll
      for (int r = 0; r < 4; r++) {
        if (OUTF == 0) ((__bf16*)Cout)[(row + r) * N + col] = (__bf16)acc[i][j][r];
        else           ((float*)Cout)[(row + r) * N + col]  = acc[i][j][r];
      }
    }
  }
}

// ---------------- RoPE + ReLU in place on q,k parts of qkv ----------------
__global__ __launch_bounds__(256) void rope_relu(__bf16* __restrict__ qkv) {
  int gid = blockIdx.x * 256 + threadIdx.x;  // 16,777,216 threads
  int dp  = gid & 31;
  int h   = (gid >> 5) & 15;
  int reg = (gid >> 9) & 1;     // 0 = q, 1 = k
  int row = gid >> 10;          // 0..16383
  int t   = row & (T_ - 1);
  // inv_freq = 10000^(-dp/32) = exp2(-dp/32 * log2(10000))
  float invf = exp2f(-(float)dp * (13.287712379549449f / 32.0f));
  float ang = (float)t * invf;
  float s, c;
  sincosf(ang, &s, &c);
  size_t base = (size_t)row * N3_ + reg * C_ + h * 64 + dp;
  float x1 = (float)qkv[base], x2 = (float)qkv[base + 32];
  float o1 = x1 * c - x2 * s;
  float o2 = x2 * c + x1 * s;
  qkv[base]      = (__bf16)fmaxf(o1, 0.0f);
  qkv[base + 32] = (__bf16)fmaxf(o2, 0.0f);
}

// ---------------- stage A: G_c = K_c^T V_c per (b,h,chunk) ----------------
#define LDW 72   // padded LDS row stride (keeps 16B alignment, reduces read conflicts)
__global__ __launch_bounds__(256) void chunk_kv(const __bf16* __restrict__ qkv,
                                                __bf16* __restrict__ G) {
  __shared__ __bf16 Kt[64 * LDW];  // Kt[d][t]
  __shared__ __bf16 Vt[64 * LDW];  // Vt[e][t]
  const int bid = blockIdx.x;
  const int c = bid & (NC_ - 1);
  const int bh = bid >> 6;
  const int h = bh & (H_ - 1);
  const int b = bh >> 4;
  const int tid = threadIdx.x;
  const size_t row0 = (size_t)b * T_ + c * 64;
  const int kcol = C_ + h * 64;
  const int vcol = 2 * C_ + h * 64;
#pragma unroll
  for (int it = 0; it < 2; ++it) {
    int task = tid + it * 256;
    int t = task >> 3;
    int d0 = (task & 7) * 8;
    const size_t rb = (row0 + t) * N3_;
    u16x8 kv = *(const u16x8*)(qkv + rb + kcol + d0);
    u16x8 vv = *(const u16x8*)(qkv + rb + vcol + d0);
#pragma unroll
    for (int j = 0; j < 8; j++) {
      ((unsigned short*)Kt)[(d0 + j) * LDW + t] = kv[j];
      ((unsigned short*)Vt)[(d0 + j) * LDW + t] = vv[j];
    }
  }
  __syncthreads();
  const int lane = tid & 63, wave = tid >> 6;
  const int gr = (wave >> 1) * 32, gc = (wave & 1) * 32;
  const int fr = lane & 15, kb = (lane >> 4) * 8;
  f32x4 acc[2][2];
#pragma unroll
  for (int i = 0; i < 2; i++)
#pragma unroll
    for (int j = 0; j < 2; j++) acc[i][j] = (f32x4)0.0f;
#pragma unroll
  for (int kk = 0; kk < 2; ++kk) {
    bf16x8 af[2], bfr[2];
#pragma unroll
    for (int i = 0; i < 2; i++)
      af[i] = *(const bf16x8*)(Kt + (gr + i * 16 + fr) * LDW + kk * 32 + kb);
#pragma unroll
    for (int j = 0; j < 2; j++)
      bfr[j] = *(const bf16x8*)(Vt + (gc + j * 16 + fr) * LDW + kk * 32 + kb);
#pragma unroll
    for (int i = 0; i < 2; i++)
#pragma unroll
      for (int j = 0; j < 2; j++)
        acc[i][j] = __builtin_amdgcn_mfma_f32_16x16x32_bf16(af[i], bfr[j], acc[i][j], 0, 0, 0);
  }
  const int rg = (lane >> 4) * 4;
  __bf16* Gb = G + (size_t)bid * 4096;
#pragma unroll
  for (int i = 0; i < 2; i++)
#pragma unroll
    for (int j = 0; j < 2; j++)
#pragma unroll
      for (int r = 0; r < 4; r++)
        Gb[(gr + i * 16 + rg + r) * 64 + gc + j * 16 + fr] = (__bf16)acc[i][j][r];
}

// ---------------- stage B: prefix over chunks; S_c = sigma0 + eta*sum_{c'<c} G ----------------
__global__ __launch_bounds__(256) void prefix_scan(const __bf16* __restrict__ G,
                                                   const float* __restrict__ sigma0,
                                                   __bf16* __restrict__ S,
                                                   float* __restrict__ sigma_out,
                                                   const float* __restrict__ eta) {
  const int bh = blockIdx.x;      // 0..63
  const int tid = threadIdx.x;
  const int d = tid >> 2;
  const int e0 = (tid & 3) * 16;  // 16 consecutive e per thread
  const float eta_s = eta[0];
  const size_t base_de = (size_t)d * 64 + e0;
  float acc[16], s0[16];
#pragma unroll
  for (int j = 0; j < 16; j++) {
    acc[j] = 0.0f;
    s0[j] = sigma0[(size_t)bh * 4096 + base_de + j];
  }
  for (int c = 0; c < NC_; ++c) {
    const size_t off = ((size_t)bh * NC_ + c) * 4096 + base_de;
    bf16x8 sv0, sv1;
#pragma unroll
    for (int j = 0; j < 8; j++) {
      sv0[j] = (__bf16)(s0[j] + eta_s * acc[j]);
      sv1[j] = (__bf16)(s0[j + 8] + eta_s * acc[j + 8]);
    }
    *(bf16x8*)(S + off)     = sv0;
    *(bf16x8*)(S + off + 8) = sv1;
    bf16x8 g0 = *(const bf16x8*)(G + off);
    bf16x8 g1 = *(const bf16x8*)(G + off + 8);
#pragma unroll
    for (int j = 0; j < 8; j++) {
      acc[j]     += (float)g0[j];
      acc[j + 8] += (float)g1[j];
    }
  }
  float* so = sigma_out + (size_t)bh * 4096 + base_de;
#pragma unroll
  for (int j = 0; j < 4; j++) {
    float4 v;
    v.x = s0[j*4+0] + eta_s * acc[j*4+0];
    v.y = s0[j*4+1] + eta_s * acc[j*4+1];
    v.z = s0[j*4+2] + eta_s * acc[j*4+2];
    v.w = s0[j*4+3] + eta_s * acc[j*4+3];
    reinterpret_cast<float4*>(so)[j] = v;
  }
}

// ---------------- stage C: O = eta*strict_tril(Q K^T) V + Q S_c ----------------
__global__ __launch_bounds__(256) void chunk_out(const __bf16* __restrict__ qkv,
                                                 const __bf16* __restrict__ S,
                                                 __bf16* __restrict__ outp,
                                                 const float* __restrict__ eta) {
  __shared__ __bf16 Qs[64 * LDW];  // [t][d]
  __shared__ __bf16 Ks[64 * LDW];  // [s][d]
  __shared__ __bf16 Vt[64 * LDW];  // [e][s]
  __shared__ __bf16 St[64 * LDW];  // [e][d]
  __shared__ __bf16 Ps[64 * LDW];  // [t][s]
  const int bid = blockIdx.x;
  const int c = bid & 63, bh = bid >> 6, h = bh & 15, b = bh >> 4;
  const int tid = threadIdx.x;
  const size_t row0 = (size_t)b * T_ + c * 64;
  const float eta_s = eta[0];
#pragma unroll
  for (int it = 0; it < 2; ++it) {
    int task = tid + it * 256;
    int t = task >> 3, d0 = (task & 7) * 8;
    const size_t rb = (row0 + t) * N3_;
    *(u16x8*)(Qs + t * LDW + d0) = *(const u16x8*)(qkv + rb + h * 64 + d0);
    *(u16x8*)(Ks + t * LDW + d0) = *(const u16x8*)(qkv + rb + C_ + h * 64 + d0);
    u16x8 vv = *(const u16x8*)(qkv + rb + 2 * C_ + h * 64 + d0);
    u16x8 sv = *(const u16x8*)(S + (size_t)bid * 4096 + t * 64 + d0);  // t = S row d here
#pragma unroll
    for (int j = 0; j < 8; j++) {
      ((unsigned short*)Vt)[(d0 + j) * LDW + t] = vv[j];
      ((unsigned short*)St)[(d0 + j) * LDW + t] = sv[j];
    }
  }
  __syncthreads();
  const int lane = tid & 63, wave = tid >> 6;
  const int qr = (wave >> 1) * 32, qc = (wave & 1) * 32;
  const int fr = lane & 15, kb = (lane >> 4) * 8, rg = (lane >> 4) * 4;
  // phase 1: P = Q K^T, strict lower mask, *eta, -> Ps (bf16)
  {
    f32x4 pacc[2][2];
#pragma unroll
    for (int i = 0; i < 2; i++)
#pragma unroll
      for (int j = 0; j < 2; j++) pacc[i][j] = (f32x4)0.0f;
#pragma unroll
    for (int kk = 0; kk < 2; ++kk) {
      bf16x8 af[2], bfr[2];
#pragma unroll
      for (int i = 0; i < 2; i++)
        af[i] = *(const bf16x8*)(Qs + (qr + i * 16 + fr) * LDW + kk * 32 + kb);
#pragma unroll
      for (int j = 0; j < 2; j++)
        bfr[j] = *(const bf16x8*)(Ks + (qc + j * 16 + fr) * LDW + kk * 32 + kb);
#pragma unroll
      for (int i = 0; i < 2; i++)
#pragma unroll
        for (int j = 0; j < 2; j++)
          pacc[i][j] = __builtin_amdgcn_mfma_f32_16x16x32_bf16(af[i], bfr[j], pacc[i][j], 0, 0, 0);
    }
#pragma unroll
    for (int i = 0; i < 2; i++)
#pragma unroll
      for (int j = 0; j < 2; j++)
#pragma unroll
        for (int r = 0; r < 4; r++) {
          int trow = qr + i * 16 + rg + r;
          int scol = qc + j * 16 + fr;
          float v = (scol < trow) ? eta_s * pacc[i][j][r] : 0.0f;
          Ps[trow * LDW + scol] = (__bf16)v;
        }
  }
  __syncthreads();
  // phase 2: O = Ps * V + Q * S
  {
    f32x4 oacc[2][2];
#pragma unroll
    for (int i = 0; i < 2; i++)
#pragma unroll
      for (int j = 0; j < 2; j++) oacc[i][j] = (f32x4)0.0f;
#pragma unroll
    for (int kk = 0; kk < 2; ++kk) {
      bf16x8 pa[2], vb[2], qa[2], sb[2];
#pragma unroll
      for (int i = 0; i < 2; i++) {
        pa[i] = *(const bf16x8*)(Ps + (qr + i * 16 + fr) * LDW + kk * 32 + kb);
        qa[i] = *(const bf16x8*)(Qs + (qr + i * 16 + fr) * LDW + kk * 32 + kb);
      }
#pragma unroll
      for (int j = 0; j < 2; j++) {
        vb[j] = *(const bf16x8*)(Vt + (qc + j * 16 + fr) * LDW + kk * 32 + kb);
        sb[j] = *(const bf16x8*)(St + (qc + j * 16 + fr) * LDW + kk * 32 + kb);
      }
#pragma unroll
      for (int i = 0; i < 2; i++)
#pragma unroll
        for (int j = 0; j < 2; j++) {
          oacc[i][j] = __builtin_amdgcn_mfma_f32_16x16x32_bf16(pa[i], vb[j], oacc[i][j], 0, 0, 0);
          oacc[i][j] = __builtin_amdgcn_mfma_f32_16x16x32_bf16(qa[i], sb[j], oacc[i][j], 0, 0, 0);
        }
    }
#pragma unroll
    for (int i = 0; i < 2; i++)
#pragma unroll
      for (int j = 0; j < 2; j++)
#pragma unroll
        for (int r = 0; r < 4; r++) {
          size_t row = row0 + qr + i * 16 + rg + r;
          int col = h * 64 + qc + j * 16 + fr;
          outp[row * C_ + col] = (__bf16)oacc[i][j][r];
        }
  }
}

extern "C" void kernel_launch(void* const* d_in, const int* in_sizes, int n_in,
                              void* d_out, int out_size, void* d_ws, size_t ws_size,
                              hipStream_t stream) {
  const float* x      = (const float*)d_in[0];
  const float* sigma0 = (const float*)d_in[1];
  const float* w_qkv  = (const float*)d_in[2];
  const float* w_proj = (const float*)d_in[3];
  const float* eta    = (const float*)d_in[4];
  float* out       = (float*)d_out;
  float* sigma_out = out + (size_t)M_ * C_;

  char* ws = (char*)d_ws;
  __bf16* xbf     = (__bf16*)(ws);               // 33,554,432 B (reused as out_pre)
  __bf16* wqkvbf  = (__bf16*)(ws + 33554432);    //  6,291,456 B
  __bf16* wprojbf = (__bf16*)(ws + 39845888);    //  2,097,152 B
  __bf16* qkvbf   = (__bf16*)(ws + 41943040);    // 100,663,296 B
  __bf16* Gws     = (__bf16*)(ws + 142606336);   // 33,554,432 B
  __bf16* Sws     = (__bf16*)(ws + 176160768);   // 33,554,432 B  (total 200 MB)

  cvt_f32_bf16<<<16384, 256, 0, stream>>>(x, xbf, 4194304);
  cvt_f32_bf16<<<3072, 256, 0, stream>>>(w_qkv, wqkvbf, 786432);
  cvt_f32_bf16<<<1024, 256, 0, stream>>>(w_proj, wprojbf, 262144);
  gemm_bt<0><<<dim3(24, 128), 256, 0, stream>>>(xbf, wqkvbf, (void*)qkvbf, M_, N3_, C_);
  rope_relu<<<65536, 256, 0, stream>>>(qkvbf);
  chunk_kv<<<4096, 256, 0, stream>>>(qkvbf, Gws);
  prefix_scan<<<64, 256, 0, stream>>>(Gws, sigma0, Sws, sigma_out, eta);
  chunk_out<<<4096, 256, 0, stream>>>(qkvbf, Sws, xbf, eta);
  gemm_bt<1><<<dim3(8, 128), 256, 0, stream>>>(xbf, wprojbf, (void*)out, M_, C_, C_);
}

// Round 6
// 296.588 us; speedup vs baseline: 1.0893x; 1.0893x over previous
//
#include <hip/hip_runtime.h>
#include <hip/hip_bf16.h>
#include <cstdint>
#include <cstddef>

#define B_   4
#define T_   4096
#define C_   1024
#define H_   16
#define NC_  64
#define M_   (B_*T_)     // 16384 rows
#define N3_  (3*C_)      // 3072

typedef __attribute__((ext_vector_type(4))) float  f32x4;
typedef __attribute__((ext_vector_type(8))) __bf16 bf16x8;
typedef __attribute__((ext_vector_type(4))) __bf16 bf16x4;
typedef __attribute__((ext_vector_type(8))) unsigned short u16x8;

__device__ __forceinline__ void glds16(void* lds, const void* g) {
  __builtin_amdgcn_global_load_lds((const __attribute__((address_space(1))) void*)g,
                                   (__attribute__((address_space(3))) void*)lds,
                                   16, 0, 0);
}

// ---------------- fp32 -> bf16 ----------------
__global__ __launch_bounds__(256) void cvt_f32_bf16(const float* __restrict__ in,
                                                    __bf16* __restrict__ out, int n4) {
  int i = blockIdx.x * 256 + threadIdx.x;
  if (i >= n4) return;
  float4 v = reinterpret_cast<const float4*>(in)[i];
  bf16x4 o;
  o[0] = (__bf16)v.x; o[1] = (__bf16)v.y; o[2] = (__bf16)v.z; o[3] = (__bf16)v.w;
  reinterpret_cast<bf16x4*>(out)[i] = o;
}

// ---------------- RoPE cos/sin table: tab[t*32+dp] = (cos, sin) of t * 10000^(-dp/32) ----------------
__global__ __launch_bounds__(256) void rope_tab(float2* __restrict__ tab) {
  int gid = blockIdx.x * 256 + threadIdx.x;  // 131072 entries
  int t = gid >> 5, dp = gid & 31;
  float invf = exp2f(-(float)dp * (13.287712379549449f / 32.0f));
  float ang = (float)t * invf;
  float s, c;
  sincosf(ang, &s, &c);
  tab[gid] = make_float2(c, s);
}

// ---------------- GEMM: C[M][N] = A[M][K] * Bt[N][K]^T  (m97-style 128x128 tile) ----------------
// FUSE==1: bf16 out, rope+relu applied to q/k column blocks (bn<16)
// FUSE==2: fp32 out
template<int FUSE>
__global__ __launch_bounds__(256) void gemm_bt(const __bf16* __restrict__ A,
                                               const __bf16* __restrict__ Bt,
                                               void* __restrict__ Cout,
                                               const float2* __restrict__ tab,
                                               int M, int N, int K) {
  __shared__ __bf16 sA[128 * 32];   // [row][k], 64B rows
  __shared__ __bf16 sB[128 * 32];
  const int tid  = threadIdx.x;
  const int lane = tid & 63;
  const int wave = tid >> 6;
  const int wr = wave >> 1, wc = wave & 1;           // 2x2 waves, each 64x64
  const int bm = blockIdx.y, bn = blockIdx.x;

  const int srow = wave * 32 + (lane >> 2);
  const int scol = (lane & 3) * 8;
  const __bf16* Ag = A  + (size_t)(bm * 128 + srow) * K + scol;
  const __bf16* Bg = Bt + (size_t)(bn * 128 + srow) * K + scol;
  __bf16* lA0 = sA + wave * 1024 + lane * 8;
  __bf16* lA1 = lA0 + 512;
  __bf16* lB0 = sB + wave * 1024 + lane * 8;
  __bf16* lB1 = lB0 + 512;

  f32x4 acc[4][4];
#pragma unroll
  for (int i = 0; i < 4; i++)
#pragma unroll
    for (int j = 0; j < 4; j++) acc[i][j] = (f32x4)0.0f;

  const int fr = lane & 15;
  const int kb = (lane >> 4) * 8;

  for (int kt = 0; kt < K; kt += 32) {
    __syncthreads();
    glds16(lA0, Ag + kt);
    glds16(lA1, Ag + (size_t)16 * K + kt);
    glds16(lB0, Bg + kt);
    glds16(lB1, Bg + (size_t)16 * K + kt);
    __syncthreads();
    bf16x8 af[4], bfr[4];
#pragma unroll
    for (int i = 0; i < 4; i++)
      af[i] = *(const bf16x8*)(sA + (wr * 64 + i * 16 + fr) * 32 + kb);
#pragma unroll
    for (int j = 0; j < 4; j++)
      bfr[j] = *(const bf16x8*)(sB + (wc * 64 + j * 16 + fr) * 32 + kb);
#pragma unroll
    for (int i = 0; i < 4; i++)
#pragma unroll
      for (int j = 0; j < 4; j++)
        acc[i][j] = __builtin_amdgcn_mfma_f32_16x16x32_bf16(af[i], bfr[j], acc[i][j], 0, 0, 0);
  }

  const int rg = (lane >> 4) * 4;
  if (FUSE == 1 && bn < 16) {
    // q/k block: rope + relu. d = j*16+fr for j in {0,1}; pair at j+2 (d+32). Uniform per block.
#pragma unroll
    for (int i = 0; i < 4; i++) {
#pragma unroll
      for (int r = 0; r < 4; r++) {
        size_t row = (size_t)bm * 128 + wr * 64 + i * 16 + rg + r;
        int t = (int)(row & (T_ - 1));
#pragma unroll
        for (int j = 0; j < 2; j++) {
          int dp = j * 16 + fr;
          float2 cs = tab[t * 32 + dp];
          float x1 = acc[i][j][r], x2 = acc[i][j + 2][r];
          float o1 = fmaxf(x1 * cs.x - x2 * cs.y, 0.0f);
          float o2 = fmaxf(x2 * cs.x + x1 * cs.y, 0.0f);
          size_t col = (size_t)bn * 128 + wc * 64 + j * 16 + fr;
          ((__bf16*)Cout)[row * N + col]      = (__bf16)o1;
          ((__bf16*)Cout)[row * N + col + 32] = (__bf16)o2;
        }
      }
    }
  } else {
#pragma unroll
    for (int i = 0; i < 4; i++) {
#pragma unroll
      for (int j = 0; j < 4; j++) {
        size_t row = (size_t)bm * 128 + wr * 64 + i * 16 + rg;
        size_t col = (size_t)bn * 128 + wc * 64 + j * 16 + fr;
#pragma unroll
        for (int r = 0; r < 4; r++) {
          if (FUSE == 2) ((float*)Cout)[(row + r) * N + col]  = acc[i][j][r];
          else           ((__bf16*)Cout)[(row + r) * N + col] = (__bf16)acc[i][j][r];
        }
      }
    }
  }
}

// ---------------- stage A: G_c = K_c^T V_c per (b,h,chunk) ----------------
#define LDW 72   // padded LDS row stride
__global__ __launch_bounds__(256) void chunk_kv(const __bf16* __restrict__ qkv,
                                                __bf16* __restrict__ G) {
  __shared__ __bf16 Kt[64 * LDW];  // Kt[d][t]
  __shared__ __bf16 Vt[64 * LDW];  // Vt[e][t]
  const int bid = blockIdx.x;
  const int c = bid & (NC_ - 1);
  const int bh = bid >> 6;
  const int h = bh & (H_ - 1);
  const int b = bh >> 4;
  const int tid = threadIdx.x;
  const size_t row0 = (size_t)b * T_ + c * 64;
  const int kcol = C_ + h * 64;
  const int vcol = 2 * C_ + h * 64;
#pragma unroll
  for (int it = 0; it < 2; ++it) {
    int task = tid + it * 256;
    int t = task >> 3;
    int d0 = (task & 7) * 8;
    const size_t rb = (row0 + t) * N3_;
    u16x8 kv = *(const u16x8*)(qkv + rb + kcol + d0);
    u16x8 vv = *(const u16x8*)(qkv + rb + vcol + d0);
#pragma unroll
    for (int j = 0; j < 8; j++) {
      ((unsigned short*)Kt)[(d0 + j) * LDW + t] = kv[j];
      ((unsigned short*)Vt)[(d0 + j) * LDW + t] = vv[j];
    }
  }
  __syncthreads();
  const int lane = tid & 63, wave = tid >> 6;
  const int gr = (wave >> 1) * 32, gc = (wave & 1) * 32;
  const int fr = lane & 15, kb = (lane >> 4) * 8;
  f32x4 acc[2][2];
#pragma unroll
  for (int i = 0; i < 2; i++)
#pragma unroll
    for (int j = 0; j < 2; j++) acc[i][j] = (f32x4)0.0f;
#pragma unroll
  for (int kk = 0; kk < 2; ++kk) {
    bf16x8 af[2], bfr[2];
#pragma unroll
    for (int i = 0; i < 2; i++)
      af[i] = *(const bf16x8*)(Kt + (gr + i * 16 + fr) * LDW + kk * 32 + kb);
#pragma unroll
    for (int j = 0; j < 2; j++)
      bfr[j] = *(const bf16x8*)(Vt + (gc + j * 16 + fr) * LDW + kk * 32 + kb);
#pragma unroll
    for (int i = 0; i < 2; i++)
#pragma unroll
      for (int j = 0; j < 2; j++)
        acc[i][j] = __builtin_amdgcn_mfma_f32_16x16x32_bf16(af[i], bfr[j], acc[i][j], 0, 0, 0);
  }
  const int rg = (lane >> 4) * 4;
  __bf16* Gb = G + (size_t)bid * 4096;
#pragma unroll
  for (int i = 0; i < 2; i++)
#pragma unroll
    for (int j = 0; j < 2; j++)
#pragma unroll
      for (int r = 0; r < 4; r++)
        Gb[(gr + i * 16 + rg + r) * 64 + gc + j * 16 + fr] = (__bf16)acc[i][j][r];
}

// ---------------- stage B: prefix over chunks; S_c = sigma0 + eta*sum_{c'<c} G ----------------
// 256 blocks: (bh, d-quarter); each thread scans 4 consecutive e over 64 chunks.
__global__ __launch_bounds__(256) void prefix_scan(const __bf16* __restrict__ G,
                                                   const float* __restrict__ sigma0,
                                                   __bf16* __restrict__ S,
                                                   float* __restrict__ sigma_out,
                                                   const float* __restrict__ eta) {
  const int blk = blockIdx.x;       // 0..255
  const int bh = blk >> 2;
  const int dq = blk & 3;
  const int tid = threadIdx.x;
  const int d = dq * 16 + (tid >> 4);
  const int e0 = (tid & 15) * 4;
  const float eta_s = eta[0];
  const size_t base_de = (size_t)d * 64 + e0;
  float acc[4], s0[4];
#pragma unroll
  for (int j = 0; j < 4; j++) {
    acc[j] = 0.0f;
    s0[j] = sigma0[(size_t)bh * 4096 + base_de + j];
  }
  for (int c = 0; c < NC_; ++c) {
    const size_t off = ((size_t)bh * NC_ + c) * 4096 + base_de;
    bf16x4 sv;
#pragma unroll
    for (int j = 0; j < 4; j++) sv[j] = (__bf16)(s0[j] + eta_s * acc[j]);
    *(bf16x4*)(S + off) = sv;
    bf16x4 g = *(const bf16x4*)(G + off);
#pragma unroll
    for (int j = 0; j < 4; j++) acc[j] += (float)g[j];
  }
  float4 v;
  v.x = s0[0] + eta_s * acc[0];
  v.y = s0[1] + eta_s * acc[1];
  v.z = s0[2] + eta_s * acc[2];
  v.w = s0[3] + eta_s * acc[3];
  *reinterpret_cast<float4*>(sigma_out + (size_t)bh * 4096 + base_de) = v;
}

// ---------------- stage C: O = eta*strict_tril(Q K^T) V + Q S_c ----------------
__global__ __launch_bounds__(256) void chunk_out(const __bf16* __restrict__ qkv,
                                                 const __bf16* __restrict__ S,
                                                 __bf16* __restrict__ outp,
                                                 const float* __restrict__ eta) {
  __shared__ __bf16 Qs[64 * LDW];  // [t][d]
  __shared__ __bf16 Ks[64 * LDW];  // [s][d]
  __shared__ __bf16 Vt[64 * LDW];  // [e][s]
  __shared__ __bf16 St[64 * LDW];  // [e][d]
  __shared__ __bf16 Ps[64 * LDW];  // [t][s]
  const int bid = blockIdx.x;
  const int c = bid & 63, bh = bid >> 6, h = bh & 15, b = bh >> 4;
  const int tid = threadIdx.x;
  const size_t row0 = (size_t)b * T_ + c * 64;
  const float eta_s = eta[0];
#pragma unroll
  for (int it = 0; it < 2; ++it) {
    int task = tid + it * 256;
    int t = task >> 3, d0 = (task & 7) * 8;
    const size_t rb = (row0 + t) * N3_;
    *(u16x8*)(Qs + t * LDW + d0) = *(const u16x8*)(qkv + rb + h * 64 + d0);
    *(u16x8*)(Ks + t * LDW + d0) = *(const u16x8*)(qkv + rb + C_ + h * 64 + d0);
    u16x8 vv = *(const u16x8*)(qkv + rb + 2 * C_ + h * 64 + d0);
    u16x8 sv = *(const u16x8*)(S + (size_t)bid * 4096 + t * 64 + d0);
#pragma unroll
    for (int j = 0; j < 8; j++) {
      ((unsigned short*)Vt)[(d0 + j) * LDW + t] = vv[j];
      ((unsigned short*)St)[(d0 + j) * LDW + t] = sv[j];
    }
  }
  __syncthreads();
  const int lane = tid & 63, wave = tid >> 6;
  const int qr = (wave >> 1) * 32, qc = (wave & 1) * 32;
  const int fr = lane & 15, kb = (lane >> 4) * 8, rg = (lane >> 4) * 4;
  // phase 1: P = Q K^T, strict lower mask, *eta, -> Ps (bf16)
  {
    f32x4 pacc[2][2];
#pragma unroll
    for (int i = 0; i < 2; i++)
#pragma unroll
      for (int j = 0; j < 2; j++) pacc[i][j] = (f32x4)0.0f;
#pragma unroll
    for (int kk = 0; kk < 2; ++kk) {
      bf16x8 af[2], bfr[2];
#pragma unroll
      for (int i = 0; i < 2; i++)
        af[i] = *(const bf16x8*)(Qs + (qr + i * 16 + fr) * LDW + kk * 32 + kb);
#pragma unroll
      for (int j = 0; j < 2; j++)
        bfr[j] = *(const bf16x8*)(Ks + (qc + j * 16 + fr) * LDW + kk * 32 + kb);
#pragma unroll
      for (int i = 0; i < 2; i++)
#pragma unroll
        for (int j = 0; j < 2; j++)
          pacc[i][j] = __builtin_amdgcn_mfma_f32_16x16x32_bf16(af[i], bfr[j], pacc[i][j], 0, 0, 0);
    }
#pragma unroll
    for (int i = 0; i < 2; i++)
#pragma unroll
      for (int j = 0; j < 2; j++)
#pragma unroll
        for (int r = 0; r < 4; r++) {
          int trow = qr + i * 16 + rg + r;
          int scol = qc + j * 16 + fr;
          float v = (scol < trow) ? eta_s * pacc[i][j][r] : 0.0f;
          Ps[trow * LDW + scol] = (__bf16)v;
        }
  }
  __syncthreads();
  // phase 2: O = Ps * V + Q * S
  {
    f32x4 oacc[2][2];
#pragma unroll
    for (int i = 0; i < 2; i++)
#pragma unroll
      for (int j = 0; j < 2; j++) oacc[i][j] = (f32x4)0.0f;
#pragma unroll
    for (int kk = 0; kk < 2; ++kk) {
      bf16x8 pa[2], vb[2], qa[2], sb[2];
#pragma unroll
      for (int i = 0; i < 2; i++) {
        pa[i] = *(const bf16x8*)(Ps + (qr + i * 16 + fr) * LDW + kk * 32 + kb);
        qa[i] = *(const bf16x8*)(Qs + (qr + i * 16 + fr) * LDW + kk * 32 + kb);
      }
#pragma unroll
      for (int j = 0; j < 2; j++) {
        vb[j] = *(const bf16x8*)(Vt + (qc + j * 16 + fr) * LDW + kk * 32 + kb);
        sb[j] = *(const bf16x8*)(St + (qc + j * 16 + fr) * LDW + kk * 32 + kb);
      }
#pragma unroll
      for (int i = 0; i < 2; i++)
#pragma unroll
        for (int j = 0; j < 2; j++) {
          oacc[i][j] = __builtin_amdgcn_mfma_f32_16x16x32_bf16(pa[i], vb[j], oacc[i][j], 0, 0, 0);
          oacc[i][j] = __builtin_amdgcn_mfma_f32_16x16x32_bf16(qa[i], sb[j], oacc[i][j], 0, 0, 0);
        }
    }
#pragma unroll
    for (int i = 0; i < 2; i++)
#pragma unroll
      for (int j = 0; j < 2; j++)
#pragma unroll
        for (int r = 0; r < 4; r++) {
          size_t row = row0 + qr + i * 16 + rg + r;
          int col = h * 64 + qc + j * 16 + fr;
          outp[row * C_ + col] = (__bf16)oacc[i][j][r];
        }
  }
}

extern "C" void kernel_launch(void* const* d_in, const int* in_sizes, int n_in,
                              void* d_out, int out_size, void* d_ws, size_t ws_size,
                              hipStream_t stream) {
  const float* x      = (const float*)d_in[0];
  const float* sigma0 = (const float*)d_in[1];
  const float* w_qkv  = (const float*)d_in[2];
  const float* w_proj = (const float*)d_in[3];
  const float* eta    = (const float*)d_in[4];
  float* out       = (float*)d_out;
  float* sigma_out = out + (size_t)M_ * C_;

  char* ws = (char*)d_ws;
  __bf16* xbf     = (__bf16*)(ws);               // 33,554,432 B (reused as out_pre)
  __bf16* wqkvbf  = (__bf16*)(ws + 33554432);    //  6,291,456 B
  __bf16* wprojbf = (__bf16*)(ws + 39845888);    //  2,097,152 B
  __bf16* qkvbf   = (__bf16*)(ws + 41943040);    // 100,663,296 B
  __bf16* Gws     = (__bf16*)(ws + 142606336);   // 33,554,432 B
  __bf16* Sws     = (__bf16*)(ws + 176160768);   // 33,554,432 B  (total 200 MB)
  // rope table lives in the first 1 MB of Sws: dead before prefix_scan writes S (stream-ordered)
  float2* tab     = (float2*)(ws + 176160768);

  rope_tab<<<512, 256, 0, stream>>>(tab);
  cvt_f32_bf16<<<16384, 256, 0, stream>>>(x, xbf, 4194304);
  cvt_f32_bf16<<<3072, 256, 0, stream>>>(w_qkv, wqkvbf, 786432);
  cvt_f32_bf16<<<1024, 256, 0, stream>>>(w_proj, wprojbf, 262144);
  gemm_bt<1><<<dim3(24, 128), 256, 0, stream>>>(xbf, wqkvbf, (void*)qkvbf, tab, M_, N3_, C_);
  chunk_kv<<<4096, 256, 0, stream>>>(qkvbf, Gws);
  prefix_scan<<<256, 256, 0, stream>>>(Gws, sigma0, Sws, sigma_out, eta);
  chunk_out<<<4096, 256, 0, stream>>>(qkvbf, Sws, xbf, eta);
  gemm_bt<2><<<dim3(8, 128), 256, 0, stream>>>(xbf, wprojbf, (void*)out, nullptr, M_, C_, C_);
}

// Round 7
// 280.383 us; speedup vs baseline: 1.1522x; 1.0578x over previous
//
#include <hip/hip_runtime.h>
#include <hip/hip_bf16.h>
#include <cstdint>
#include <cstddef>

#define B_   4
#define T_   4096
#define C_   1024
#define H_   16
#define NC_  64
#define M_   (B_*T_)     // 16384 rows
#define N3_  (3*C_)      // 3072
#define G1_NT 16         // K=1024 / BK=64

typedef __attribute__((ext_vector_type(4))) float  f32x4;
typedef __attribute__((ext_vector_type(8))) __bf16 bf16x8;
typedef __attribute__((ext_vector_type(4))) __bf16 bf16x4;
typedef __attribute__((ext_vector_type(8))) unsigned short u16x8;

__device__ __forceinline__ void glds16(void* lds, const void* g) {
  __builtin_amdgcn_global_load_lds((const __attribute__((address_space(1))) void*)g,
                                   (__attribute__((address_space(3))) void*)lds,
                                   16, 0, 0);
}
#define MFMA_BF16 __builtin_amdgcn_mfma_f32_16x16x32_bf16

// ---------------- fp32 -> bf16 ----------------
__global__ __launch_bounds__(256) void cvt_f32_bf16(const float* __restrict__ in,
                                                    __bf16* __restrict__ out, int n4) {
  int i = blockIdx.x * 256 + threadIdx.x;
  if (i >= n4) return;
  float4 v = reinterpret_cast<const float4*>(in)[i];
  bf16x4 o;
  o[0] = (__bf16)v.x; o[1] = (__bf16)v.y; o[2] = (__bf16)v.z; o[3] = (__bf16)v.w;
  reinterpret_cast<bf16x4*>(out)[i] = o;
}

// ---------------- RoPE cos/sin table ----------------
__global__ __launch_bounds__(256) void rope_tab(float2* __restrict__ tab) {
  int gid = blockIdx.x * 256 + threadIdx.x;  // 131072 entries
  int t = gid >> 5, dp = gid & 31;
  float invf = exp2f(-(float)dp * (13.287712379549449f / 32.0f));
  float ang = (float)t * invf;
  float s, c;
  sincosf(ang, &s, &c);
  tab[gid] = make_float2(c, s);
}

// ============ GEMM1: qkv = x @ w_qkv^T, fused rope+relu. 256x128 tile, BK=64, ============
// ============ 3-buffer pipeline, counted vmcnt, T2 swizzle, setprio            ============
// grid (N3_/128=24, M_/256=64), 512 threads (8 waves: wm=wave>>1 in 0..3, wn=wave&1)
__global__ __launch_bounds__(512) void gemm1_pipe(const __bf16* __restrict__ A,
                                                  const __bf16* __restrict__ Bt,
                                                  __bf16* __restrict__ Cout,
                                                  const float2* __restrict__ tab) {
  __shared__ __bf16 sA[3][256 * 64];   // 3 x 32 KB, [row][64k], swizzled 16B slots
  __shared__ __bf16 sB[3][128 * 64];   // 3 x 16 KB
  const int tid  = threadIdx.x;
  const int lane = tid & 63;
  const int wave = tid >> 6;
  const int wm = wave >> 1, wn = wave & 1;
  const int bm = blockIdx.y, bn = blockIdx.x;
  const int fr = lane & 15, kq = lane >> 4;
  const int fr7 = fr & 7;
  const int K = C_;

  // staging: per issue, 512 threads x 16B = 8KB = 64 rows. Linear LDS dest (tid*16),
  // inverse-swizzled global source slot: s = (tid&7) ^ ((tid>>3)&7).
  const int r_loc = tid >> 3;
  const int sslot = (tid & 7) ^ (r_loc & 7);
  const __bf16* Ag = A  + (size_t)(bm * 256 + r_loc) * K + sslot * 8;
  const __bf16* Bg = Bt + (size_t)(bn * 128 + r_loc) * K + sslot * 8;

  f32x4 acc[4][4];
#pragma unroll
  for (int i = 0; i < 4; i++)
#pragma unroll
    for (int j = 0; j < 4; j++) acc[i][j] = (f32x4)0.0f;

  // prologue: stage tiles 0 and 1 (6 issues each)
#pragma unroll
  for (int t = 0; t < 2; ++t) {
#pragma unroll
    for (int q = 0; q < 4; ++q)
      glds16((char*)sA[t] + q * 8192 + tid * 16, Ag + (size_t)q * 64 * K + t * 64);
#pragma unroll
    for (int q = 0; q < 2; ++q)
      glds16((char*)sB[t] + q * 8192 + tid * 16, Bg + (size_t)q * 64 * K + t * 64);
  }
  asm volatile("s_waitcnt vmcnt(6)" ::: "memory");   // tile0 resident, tile1 in flight
  __builtin_amdgcn_sched_barrier(0);
  __builtin_amdgcn_s_barrier();

  bf16x8 af[4][2], bf01[2][2], bf23[2][2];
  for (int t = 0; t < G1_NT; ++t) {
    const int buf  = t % 3;
    const int nbuf = (t + 2) % 3;           // freed by tile t-1's end barrier
    const bool dostage = (t + 2 < G1_NT);
    const int kb2 = (t + 2) * 64;
    const __bf16* Ab = (const __bf16*)sA[buf];
    const __bf16* Bb = (const __bf16*)sB[buf];

    // ---- phase 0: stage A q0..q2 of t+2; read A frags + B j01; 16 MFMA ----
    if (dostage) {
      glds16((char*)sA[nbuf] +     0 + tid * 16, Ag + (size_t)0 * 64 * K + kb2);
      glds16((char*)sA[nbuf] +  8192 + tid * 16, Ag + (size_t)1 * 64 * K + kb2);
      glds16((char*)sA[nbuf] + 16384 + tid * 16, Ag + (size_t)2 * 64 * K + kb2);
    }
#pragma unroll
    for (int i = 0; i < 4; ++i)
#pragma unroll
      for (int kk = 0; kk < 2; ++kk)
        af[i][kk] = *(const bf16x8*)((const char*)Ab + (wm * 64 + i * 16 + fr) * 128 +
                                     (((kk << 2) | kq) ^ fr7) * 16);
#pragma unroll
    for (int j = 0; j < 2; ++j)
#pragma unroll
      for (int kk = 0; kk < 2; ++kk)
        bf01[j][kk] = *(const bf16x8*)((const char*)Bb + (wn * 64 + j * 16 + fr) * 128 +
                                       (((kk << 2) | kq) ^ fr7) * 16);
    __builtin_amdgcn_s_barrier();
    __builtin_amdgcn_s_setprio(1);
#pragma unroll
    for (int i = 0; i < 4; ++i)
#pragma unroll
      for (int j = 0; j < 2; ++j) {
        acc[i][j] = MFMA_BF16(af[i][0], bf01[j][0], acc[i][j], 0, 0, 0);
        acc[i][j] = MFMA_BF16(af[i][1], bf01[j][1], acc[i][j], 0, 0, 0);
      }
    __builtin_amdgcn_s_setprio(0);
    __builtin_amdgcn_s_barrier();

    // ---- phase 1: stage A q3 + B q0,q1 of t+2; read B j23; 16 MFMA ----
    if (dostage) {
      glds16((char*)sA[nbuf] + 24576 + tid * 16, Ag + (size_t)3 * 64 * K + kb2);
      glds16((char*)sB[nbuf] +     0 + tid * 16, Bg + (size_t)0 * 64 * K + kb2);
      glds16((char*)sB[nbuf] +  8192 + tid * 16, Bg + (size_t)1 * 64 * K + kb2);
    }
#pragma unroll
    for (int j = 0; j < 2; ++j)
#pragma unroll
      for (int kk = 0; kk < 2; ++kk)
        bf23[j][kk] = *(const bf16x8*)((const char*)Bb + (wn * 64 + (j + 2) * 16 + fr) * 128 +
                                       (((kk << 2) | kq) ^ fr7) * 16);
    __builtin_amdgcn_s_barrier();
    __builtin_amdgcn_s_setprio(1);
#pragma unroll
    for (int i = 0; i < 4; ++i)
#pragma unroll
      for (int j = 0; j < 2; ++j) {
        acc[i][j + 2] = MFMA_BF16(af[i][0], bf23[j][0], acc[i][j + 2], 0, 0, 0);
        acc[i][j + 2] = MFMA_BF16(af[i][1], bf23[j][1], acc[i][j + 2], 0, 0, 0);
      }
    __builtin_amdgcn_s_setprio(0);
    // boundary: tile t+1 must be resident past this barrier; t+2's 6 loads may fly
    if (t < G1_NT - 1) {
      if (dostage) asm volatile("s_waitcnt vmcnt(6)" ::: "memory");
      else         asm volatile("s_waitcnt vmcnt(0)" ::: "memory");
      __builtin_amdgcn_sched_barrier(0);
    }
    __builtin_amdgcn_s_barrier();
  }

  // epilogue: rope+relu on q/k column blocks (bn<16), plain bf16 otherwise
  const int rg4 = kq * 4;
  if (bn < 16) {
#pragma unroll
    for (int i = 0; i < 4; ++i)
#pragma unroll
      for (int r = 0; r < 4; ++r) {
        size_t row = (size_t)bm * 256 + wm * 64 + i * 16 + rg4 + r;
        int tt = (int)(row & (T_ - 1));
#pragma unroll
        for (int j = 0; j < 2; ++j) {
          int dp = j * 16 + fr;
          float2 cs = tab[tt * 32 + dp];
          float x1 = acc[i][j][r], x2 = acc[i][j + 2][r];
          float o1 = fmaxf(x1 * cs.x - x2 * cs.y, 0.0f);
          float o2 = fmaxf(x2 * cs.x + x1 * cs.y, 0.0f);
          size_t col = (size_t)bn * 128 + wn * 64 + j * 16 + fr;
          Cout[row * N3_ + col]      = (__bf16)o1;
          Cout[row * N3_ + col + 32] = (__bf16)o2;
        }
      }
  } else {
#pragma unroll
    for (int i = 0; i < 4; ++i)
#pragma unroll
      for (int j = 0; j < 4; ++j) {
        size_t row = (size_t)bm * 256 + wm * 64 + i * 16 + rg4;
        size_t col = (size_t)bn * 128 + wn * 64 + j * 16 + fr;
#pragma unroll
        for (int r = 0; r < 4; ++r)
          Cout[(row + r) * N3_ + col] = (__bf16)acc[i][j][r];
      }
  }
}

// ---------------- GEMM2 (m97-style 128x128): out = out_pre @ w_proj^T, fp32 out ----------------
__global__ __launch_bounds__(256) void gemm_bt_f32(const __bf16* __restrict__ A,
                                                   const __bf16* __restrict__ Bt,
                                                   float* __restrict__ Cout,
                                                   int M, int N, int K) {
  __shared__ __bf16 sA[128 * 32];
  __shared__ __bf16 sB[128 * 32];
  const int tid  = threadIdx.x;
  const int lane = tid & 63;
  const int wave = tid >> 6;
  const int wr = wave >> 1, wc = wave & 1;
  const int bm = blockIdx.y, bn = blockIdx.x;

  const int srow = wave * 32 + (lane >> 2);
  const int scol = (lane & 3) * 8;
  const __bf16* Ag = A  + (size_t)(bm * 128 + srow) * K + scol;
  const __bf16* Bg = Bt + (size_t)(bn * 128 + srow) * K + scol;
  __bf16* lA0 = sA + wave * 1024 + lane * 8;
  __bf16* lA1 = lA0 + 512;
  __bf16* lB0 = sB + wave * 1024 + lane * 8;
  __bf16* lB1 = lB0 + 512;

  f32x4 acc[4][4];
#pragma unroll
  for (int i = 0; i < 4; i++)
#pragma unroll
    for (int j = 0; j < 4; j++) acc[i][j] = (f32x4)0.0f;

  const int fr = lane & 15;
  const int kb = (lane >> 4) * 8;

  for (int kt = 0; kt < K; kt += 32) {
    __syncthreads();
    glds16(lA0, Ag + kt);
    glds16(lA1, Ag + (size_t)16 * K + kt);
    glds16(lB0, Bg + kt);
    glds16(lB1, Bg + (size_t)16 * K + kt);
    __syncthreads();
    bf16x8 af[4], bfr[4];
#pragma unroll
    for (int i = 0; i < 4; i++)
      af[i] = *(const bf16x8*)(sA + (wr * 64 + i * 16 + fr) * 32 + kb);
#pragma unroll
    for (int j = 0; j < 4; j++)
      bfr[j] = *(const bf16x8*)(sB + (wc * 64 + j * 16 + fr) * 32 + kb);
#pragma unroll
    for (int i = 0; i < 4; i++)
#pragma unroll
      for (int j = 0; j < 4; j++)
        acc[i][j] = MFMA_BF16(af[i], bfr[j], acc[i][j], 0, 0, 0);
  }

  const int rg = (lane >> 4) * 4;
#pragma unroll
  for (int i = 0; i < 4; i++)
#pragma unroll
    for (int j = 0; j < 4; j++) {
      size_t row = (size_t)bm * 128 + wr * 64 + i * 16 + rg;
      size_t col = (size_t)bn * 128 + wc * 64 + j * 16 + fr;
#pragma unroll
      for (int r = 0; r < 4; r++)
        Cout[(row + r) * N + col] = acc[i][j][r];
    }
}

// ---------------- stage A: G_c = K_c^T V_c per (b,h,chunk) ----------------
#define LDW 72
__global__ __launch_bounds__(256) void chunk_kv(const __bf16* __restrict__ qkv,
                                                __bf16* __restrict__ G) {
  __shared__ __bf16 Kt[64 * LDW];
  __shared__ __bf16 Vt[64 * LDW];
  const int bid = blockIdx.x;
  const int c = bid & (NC_ - 1);
  const int bh = bid >> 6;
  const int h = bh & (H_ - 1);
  const int b = bh >> 4;
  const int tid = threadIdx.x;
  const size_t row0 = (size_t)b * T_ + c * 64;
  const int kcol = C_ + h * 64;
  const int vcol = 2 * C_ + h * 64;
#pragma unroll
  for (int it = 0; it < 2; ++it) {
    int task = tid + it * 256;
    int t = task >> 3;
    int d0 = (task & 7) * 8;
    const size_t rb = (row0 + t) * N3_;
    u16x8 kv = *(const u16x8*)(qkv + rb + kcol + d0);
    u16x8 vv = *(const u16x8*)(qkv + rb + vcol + d0);
#pragma unroll
    for (int j = 0; j < 8; j++) {
      ((unsigned short*)Kt)[(d0 + j) * LDW + t] = kv[j];
      ((unsigned short*)Vt)[(d0 + j) * LDW + t] = vv[j];
    }
  }
  __syncthreads();
  const int lane = tid & 63, wave = tid >> 6;
  const int gr = (wave >> 1) * 32, gc = (wave & 1) * 32;
  const int fr = lane & 15, kb = (lane >> 4) * 8;
  f32x4 acc[2][2];
#pragma unroll
  for (int i = 0; i < 2; i++)
#pragma unroll
    for (int j = 0; j < 2; j++) acc[i][j] = (f32x4)0.0f;
#pragma unroll
  for (int kk = 0; kk < 2; ++kk) {
    bf16x8 af[2], bfr[2];
#pragma unroll
    for (int i = 0; i < 2; i++)
      af[i] = *(const bf16x8*)(Kt + (gr + i * 16 + fr) * LDW + kk * 32 + kb);
#pragma unroll
    for (int j = 0; j < 2; j++)
      bfr[j] = *(const bf16x8*)(Vt + (gc + j * 16 + fr) * LDW + kk * 32 + kb);
#pragma unroll
    for (int i = 0; i < 2; i++)
#pragma unroll
      for (int j = 0; j < 2; j++)
        acc[i][j] = MFMA_BF16(af[i], bfr[j], acc[i][j], 0, 0, 0);
  }
  const int rg = (lane >> 4) * 4;
  __bf16* Gb = G + (size_t)bid * 4096;
#pragma unroll
  for (int i = 0; i < 2; i++)
#pragma unroll
    for (int j = 0; j < 2; j++)
#pragma unroll
      for (int r = 0; r < 4; r++)
        Gb[(gr + i * 16 + rg + r) * 64 + gc + j * 16 + fr] = (__bf16)acc[i][j][r];
}

// ---------------- stage B: prefix over chunks ----------------
__global__ __launch_bounds__(256) void prefix_scan(const __bf16* __restrict__ G,
                                                   const float* __restrict__ sigma0,
                                                   __bf16* __restrict__ S,
                                                   float* __restrict__ sigma_out,
                                                   const float* __restrict__ eta) {
  const int blk = blockIdx.x;       // 0..255
  const int bh = blk >> 2;
  const int dq = blk & 3;
  const int tid = threadIdx.x;
  const int d = dq * 16 + (tid >> 4);
  const int e0 = (tid & 15) * 4;
  const float eta_s = eta[0];
  const size_t base_de = (size_t)d * 64 + e0;
  float acc[4], s0[4];
#pragma unroll
  for (int j = 0; j < 4; j++) {
    acc[j] = 0.0f;
    s0[j] = sigma0[(size_t)bh * 4096 + base_de + j];
  }
  for (int c = 0; c < NC_; ++c) {
    const size_t off = ((size_t)bh * NC_ + c) * 4096 + base_de;
    bf16x4 sv;
#pragma unroll
    for (int j = 0; j < 4; j++) sv[j] = (__bf16)(s0[j] + eta_s * acc[j]);
    *(bf16x4*)(S + off) = sv;
    bf16x4 g = *(const bf16x4*)(G + off);
#pragma unroll
    for (int j = 0; j < 4; j++) acc[j] += (float)g[j];
  }
  float4 v;
  v.x = s0[0] + eta_s * acc[0];
  v.y = s0[1] + eta_s * acc[1];
  v.z = s0[2] + eta_s * acc[2];
  v.w = s0[3] + eta_s * acc[3];
  *reinterpret_cast<float4*>(sigma_out + (size_t)bh * 4096 + base_de) = v;
}

// ---------------- stage C: O = eta*strict_tril(Q K^T) V + Q S_c ----------------
__global__ __launch_bounds__(256) void chunk_out(const __bf16* __restrict__ qkv,
                                                 const __bf16* __restrict__ S,
                                                 __bf16* __restrict__ outp,
                                                 const float* __restrict__ eta) {
  __shared__ __bf16 Qs[64 * LDW];
  __shared__ __bf16 Ks[64 * LDW];
  __shared__ __bf16 Vt[64 * LDW];
  __shared__ __bf16 St[64 * LDW];
  __shared__ __bf16 Ps[64 * LDW];
  const int bid = blockIdx.x;
  const int c = bid & 63, bh = bid >> 6, h = bh & 15, b = bh >> 4;
  const int tid = threadIdx.x;
  const size_t row0 = (size_t)b * T_ + c * 64;
  const float eta_s = eta[0];
#pragma unroll
  for (int it = 0; it < 2; ++it) {
    int task = tid + it * 256;
    int t = task >> 3, d0 = (task & 7) * 8;
    const size_t rb = (row0 + t) * N3_;
    *(u16x8*)(Qs + t * LDW + d0) = *(const u16x8*)(qkv + rb + h * 64 + d0);
    *(u16x8*)(Ks + t * LDW + d0) = *(const u16x8*)(qkv + rb + C_ + h * 64 + d0);
    u16x8 vv = *(const u16x8*)(qkv + rb + 2 * C_ + h * 64 + d0);
    u16x8 sv = *(const u16x8*)(S + (size_t)bid * 4096 + t * 64 + d0);
#pragma unroll
    for (int j = 0; j < 8; j++) {
      ((unsigned short*)Vt)[(d0 + j) * LDW + t] = vv[j];
      ((unsigned short*)St)[(d0 + j) * LDW + t] = sv[j];
    }
  }
  __syncthreads();
  const int lane = tid & 63, wave = tid >> 6;
  const int qr = (wave >> 1) * 32, qc = (wave & 1) * 32;
  const int fr = lane & 15, kb = (lane >> 4) * 8, rg = (lane >> 4) * 4;
  {
    f32x4 pacc[2][2];
#pragma unroll
    for (int i = 0; i < 2; i++)
#pragma unroll
      for (int j = 0; j < 2; j++) pacc[i][j] = (f32x4)0.0f;
#pragma unroll
    for (int kk = 0; kk < 2; ++kk) {
      bf16x8 af[2], bfr[2];
#pragma unroll
      for (int i = 0; i < 2; i++)
        af[i] = *(const bf16x8*)(Qs + (qr + i * 16 + fr) * LDW + kk * 32 + kb);
#pragma unroll
      for (int j = 0; j < 2; j++)
        bfr[j] = *(const bf16x8*)(Ks + (qc + j * 16 + fr) * LDW + kk * 32 + kb);
#pragma unroll
      for (int i = 0; i < 2; i++)
#pragma unroll
        for (int j = 0; j < 2; j++)
          pacc[i][j] = MFMA_BF16(af[i], bfr[j], pacc[i][j], 0, 0, 0);
    }
#pragma unroll
    for (int i = 0; i < 2; i++)
#pragma unroll
      for (int j = 0; j < 2; j++)
#pragma unroll
        for (int r = 0; r < 4; r++) {
          int trow = qr + i * 16 + rg + r;
          int scol = qc + j * 16 + fr;
          float v = (scol < trow) ? eta_s * pacc[i][j][r] : 0.0f;
          Ps[trow * LDW + scol] = (__bf16)v;
        }
  }
  __syncthreads();
  {
    f32x4 oacc[2][2];
#pragma unroll
    for (int i = 0; i < 2; i++)
#pragma unroll
      for (int j = 0; j < 2; j++) oacc[i][j] = (f32x4)0.0f;
#pragma unroll
    for (int kk = 0; kk < 2; ++kk) {
      bf16x8 pa[2], vb[2], qa[2], sb[2];
#pragma unroll
      for (int i = 0; i < 2; i++) {
        pa[i] = *(const bf16x8*)(Ps + (qr + i * 16 + fr) * LDW + kk * 32 + kb);
        qa[i] = *(const bf16x8*)(Qs + (qr + i * 16 + fr) * LDW + kk * 32 + kb);
      }
#pragma unroll
      for (int j = 0; j < 2; j++) {
        vb[j] = *(const bf16x8*)(Vt + (qc + j * 16 + fr) * LDW + kk * 32 + kb);
        sb[j] = *(const bf16x8*)(St + (qc + j * 16 + fr) * LDW + kk * 32 + kb);
      }
#pragma unroll
      for (int i = 0; i < 2; i++)
#pragma unroll
        for (int j = 0; j < 2; j++) {
          oacc[i][j] = MFMA_BF16(pa[i], vb[j], oacc[i][j], 0, 0, 0);
          oacc[i][j] = MFMA_BF16(qa[i], sb[j], oacc[i][j], 0, 0, 0);
        }
    }
#pragma unroll
    for (int i = 0; i < 2; i++)
#pragma unroll
      for (int j = 0; j < 2; j++)
#pragma unroll
        for (int r = 0; r < 4; r++) {
          size_t row = row0 + qr + i * 16 + rg + r;
          int col = h * 64 + qc + j * 16 + fr;
          outp[row * C_ + col] = (__bf16)oacc[i][j][r];
        }
  }
}

extern "C" void kernel_launch(void* const* d_in, const int* in_sizes, int n_in,
                              void* d_out, int out_size, void* d_ws, size_t ws_size,
                              hipStream_t stream) {
  const float* x      = (const float*)d_in[0];
  const float* sigma0 = (const float*)d_in[1];
  const float* w_qkv  = (const float*)d_in[2];
  const float* w_proj = (const float*)d_in[3];
  const float* eta    = (const float*)d_in[4];
  float* out       = (float*)d_out;
  float* sigma_out = out + (size_t)M_ * C_;

  char* ws = (char*)d_ws;
  __bf16* xbf     = (__bf16*)(ws);               // 32 MB (reused as out_pre)
  __bf16* wqkvbf  = (__bf16*)(ws + 33554432);
  __bf16* wprojbf = (__bf16*)(ws + 39845888);
  __bf16* qkvbf   = (__bf16*)(ws + 41943040);    // 96 MB
  __bf16* Gws     = (__bf16*)(ws + 142606336);   // 32 MB
  __bf16* Sws     = (__bf16*)(ws + 176160768);   // 32 MB
  float2* tab     = (float2*)(ws + 176160768);   // 1 MB, dead before prefix_scan writes S

  rope_tab<<<512, 256, 0, stream>>>(tab);
  cvt_f32_bf16<<<16384, 256, 0, stream>>>(x, xbf, 4194304);
  cvt_f32_bf16<<<3072, 256, 0, stream>>>(w_qkv, wqkvbf, 786432);
  cvt_f32_bf16<<<1024, 256, 0, stream>>>(w_proj, wprojbf, 262144);
  gemm1_pipe<<<dim3(24, 64), 512, 0, stream>>>(xbf, wqkvbf, qkvbf, tab);
  chunk_kv<<<4096, 256, 0, stream>>>(qkvbf, Gws);
  prefix_scan<<<256, 256, 0, stream>>>(Gws, sigma0, Sws, sigma_out, eta);
  chunk_out<<<4096, 256, 0, stream>>>(qkvbf, Sws, xbf, eta);
  gemm_bt_f32<<<dim3(8, 128), 256, 0, stream>>>(xbf, wprojbf, out, M_, C_, C_);
}

// Round 10
// 270.666 us; speedup vs baseline: 1.1936x; 1.0359x over previous
//
#include <hip/hip_runtime.h>
#include <hip/hip_bf16.h>
#include <cstdint>
#include <cstddef>

#define B_   4
#define T_   4096
#define C_   1024
#define H_   16
#define NC_  64
#define M_   (B_*T_)     // 16384 rows
#define N3_  (3*C_)      // 3072
#define G1_NT 16         // K=1024 / BK=64

typedef __attribute__((ext_vector_type(4))) float  f32x4;
typedef __attribute__((ext_vector_type(8))) __bf16 bf16x8;
typedef __attribute__((ext_vector_type(4))) __bf16 bf16x4;
typedef __attribute__((ext_vector_type(8))) unsigned short u16x8;

__device__ __forceinline__ void glds16(void* lds, const void* g) {
  __builtin_amdgcn_global_load_lds((const __attribute__((address_space(1))) void*)g,
                                   (__attribute__((address_space(3))) void*)lds,
                                   16, 0, 0);
}
#define MFMA_BF16 __builtin_amdgcn_mfma_f32_16x16x32_bf16

// ---------------- fp32 -> bf16 ----------------
__global__ __launch_bounds__(256) void cvt_f32_bf16(const float* __restrict__ in,
                                                    __bf16* __restrict__ out, int n4) {
  int i = blockIdx.x * 256 + threadIdx.x;
  if (i >= n4) return;
  float4 v = reinterpret_cast<const float4*>(in)[i];
  bf16x4 o;
  o[0] = (__bf16)v.x; o[1] = (__bf16)v.y; o[2] = (__bf16)v.z; o[3] = (__bf16)v.w;
  reinterpret_cast<bf16x4*>(out)[i] = o;
}

// ---------------- RoPE cos/sin table ----------------
__global__ __launch_bounds__(256) void rope_tab(float2* __restrict__ tab) {
  int gid = blockIdx.x * 256 + threadIdx.x;  // 131072 entries
  int t = gid >> 5, dp = gid & 31;
  float invf = exp2f(-(float)dp * (13.287712379549449f / 32.0f));
  float ang = (float)t * invf;
  float s, c;
  sincosf(ang, &s, &c);
  tab[gid] = make_float2(c, s);
}

// ============ GEMM1: qkv = x @ w_qkv^T, fused rope+relu. 256x128 tile, BK=64, ============
// ============ 3-buffer pipeline, ONE barrier/tile (counted vmcnt), T2 swizzle ============
// grid (N3_/128=24, M_/256=64), 512 threads (8 waves: wm=wave>>1 in 0..3, wn=wave&1)
__global__ __launch_bounds__(512) void gemm1_pipe(const __bf16* __restrict__ A,
                                                  const __bf16* __restrict__ Bt,
                                                  __bf16* __restrict__ Cout,
                                                  const float2* __restrict__ tab) {
  __shared__ __bf16 sA[3][256 * 64];   // 3 x 32 KB, [row][64k], swizzled 16B slots
  __shared__ __bf16 sB[3][128 * 64];   // 3 x 16 KB
  const int tid  = threadIdx.x;
  const int lane = tid & 63;
  const int wave = tid >> 6;
  const int wm = wave >> 1, wn = wave & 1;
  const int bm = blockIdx.y, bn = blockIdx.x;
  const int fr = lane & 15, kq = lane >> 4;
  const int fr7 = fr & 7;
  const int K = C_;

  // staging: per issue, 512 threads x 16B = 8KB = 64 rows. Linear LDS dest (tid*16),
  // inverse-swizzled global source slot: s = (tid&7) ^ ((tid>>3)&7).
  const int r_loc = tid >> 3;
  const int sslot = (tid & 7) ^ (r_loc & 7);
  const __bf16* Ag = A  + (size_t)(bm * 256 + r_loc) * K + sslot * 8;
  const __bf16* Bg = Bt + (size_t)(bn * 128 + r_loc) * K + sslot * 8;

  f32x4 acc[4][4];
#pragma unroll
  for (int i = 0; i < 4; i++)
#pragma unroll
    for (int j = 0; j < 4; j++) acc[i][j] = (f32x4)0.0f;

  // prologue: stage tiles 0 and 1 (6 issues each)
#pragma unroll
  for (int t = 0; t < 2; ++t) {
#pragma unroll
    for (int q = 0; q < 4; ++q)
      glds16((char*)sA[t] + q * 8192 + tid * 16, Ag + (size_t)q * 64 * K + t * 64);
#pragma unroll
    for (int q = 0; q < 2; ++q)
      glds16((char*)sB[t] + q * 8192 + tid * 16, Bg + (size_t)q * 64 * K + t * 64);
  }
  asm volatile("s_waitcnt vmcnt(6)" ::: "memory");   // tile0 resident, tile1 in flight
  __builtin_amdgcn_sched_barrier(0);
  __builtin_amdgcn_s_barrier();

  bf16x8 af[4][2], bfr[4][2];
  for (int t = 0; t < G1_NT; ++t) {
    const int buf  = t % 3;
    const int nbuf = (t + 2) % 3;           // freed by tile t-1's end barrier
    const bool dostage = (t + 2 < G1_NT);
    const int kb2 = (t + 2) * 64;
    const __bf16* Ab = (const __bf16*)sA[buf];
    const __bf16* Bb = (const __bf16*)sB[buf];

    // stage tile t+2 (6 x glds); in flight across this tile's MFMA window
    if (dostage) {
      glds16((char*)sA[nbuf] +     0 + tid * 16, Ag + (size_t)0 * 64 * K + kb2);
      glds16((char*)sA[nbuf] +  8192 + tid * 16, Ag + (size_t)1 * 64 * K + kb2);
      glds16((char*)sA[nbuf] + 16384 + tid * 16, Ag + (size_t)2 * 64 * K + kb2);
      glds16((char*)sA[nbuf] + 24576 + tid * 16, Ag + (size_t)3 * 64 * K + kb2);
      glds16((char*)sB[nbuf] +     0 + tid * 16, Bg + (size_t)0 * 64 * K + kb2);
      glds16((char*)sB[nbuf] +  8192 + tid * 16, Bg + (size_t)1 * 64 * K + kb2);
    }

    // read all fragments (16 x ds_read_b128); compiler pipelines via counted lgkmcnt
#pragma unroll
    for (int i = 0; i < 4; ++i)
#pragma unroll
      for (int kk = 0; kk < 2; ++kk)
        af[i][kk] = *(const bf16x8*)((const char*)Ab + (wm * 64 + i * 16 + fr) * 128 +
                                     (((kk << 2) | kq) ^ fr7) * 16);
#pragma unroll
    for (int j = 0; j < 4; ++j)
#pragma unroll
      for (int kk = 0; kk < 2; ++kk)
        bfr[j][kk] = *(const bf16x8*)((const char*)Bb + (wn * 64 + j * 16 + fr) * 128 +
                                      (((kk << 2) | kq) ^ fr7) * 16);

    __builtin_amdgcn_s_setprio(1);
#pragma unroll
    for (int i = 0; i < 4; ++i)
#pragma unroll
      for (int j = 0; j < 4; ++j) {
        acc[i][j] = MFMA_BF16(af[i][0], bfr[j][0], acc[i][j], 0, 0, 0);
        acc[i][j] = MFMA_BF16(af[i][1], bfr[j][1], acc[i][j], 0, 0, 0);
      }
    __builtin_amdgcn_s_setprio(0);

    // tile boundary: t+1 must be resident past this barrier; t+2's 6 loads may fly
    if (t < G1_NT - 1) {
      if (dostage) asm volatile("s_waitcnt vmcnt(6)" ::: "memory");
      else         asm volatile("s_waitcnt vmcnt(0)" ::: "memory");
      __builtin_amdgcn_sched_barrier(0);
      __builtin_amdgcn_s_barrier();
    }
  }

  // epilogue: rope+relu on q/k column blocks (bn<16), plain bf16 otherwise
  const int rg4 = kq * 4;
  if (bn < 16) {
#pragma unroll
    for (int i = 0; i < 4; ++i)
#pragma unroll
      for (int r = 0; r < 4; ++r) {
        size_t row = (size_t)bm * 256 + wm * 64 + i * 16 + rg4 + r;
        int tt = (int)(row & (T_ - 1));
#pragma unroll
        for (int j = 0; j < 2; ++j) {
          int dp = j * 16 + fr;
          float2 cs = tab[tt * 32 + dp];
          float x1 = acc[i][j][r], x2 = acc[i][j + 2][r];
          float o1 = fmaxf(x1 * cs.x - x2 * cs.y, 0.0f);
          float o2 = fmaxf(x2 * cs.x + x1 * cs.y, 0.0f);
          size_t col = (size_t)bn * 128 + wn * 64 + j * 16 + fr;
          Cout[row * N3_ + col]      = (__bf16)o1;
          Cout[row * N3_ + col + 32] = (__bf16)o2;
        }
      }
  } else {
#pragma unroll
    for (int i = 0; i < 4; ++i)
#pragma unroll
      for (int j = 0; j < 4; ++j) {
        size_t row = (size_t)bm * 256 + wm * 64 + i * 16 + rg4;
        size_t col = (size_t)bn * 128 + wn * 64 + j * 16 + fr;
#pragma unroll
        for (int r = 0; r < 4; ++r)
          Cout[(row + r) * N3_ + col] = (__bf16)acc[i][j][r];
      }
  }
}

// ---------------- GEMM2 (m97-style 128x128): out = out_pre @ w_proj^T, fp32 out ----------------
__global__ __launch_bounds__(256) void gemm_bt_f32(const __bf16* __restrict__ A,
                                                   const __bf16* __restrict__ Bt,
                                                   float* __restrict__ Cout,
                                                   int M, int N, int K) {
  __shared__ __bf16 sA[128 * 32];
  __shared__ __bf16 sB[128 * 32];
  const int tid  = threadIdx.x;
  const int lane = tid & 63;
  const int wave = tid >> 6;
  const int wr = wave >> 1, wc = wave & 1;
  const int bm = blockIdx.y, bn = blockIdx.x;

  const int srow = wave * 32 + (lane >> 2);
  const int scol = (lane & 3) * 8;
  const __bf16* Ag = A  + (size_t)(bm * 128 + srow) * K + scol;
  const __bf16* Bg = Bt + (size_t)(bn * 128 + srow) * K + scol;
  __bf16* lA0 = sA + wave * 1024 + lane * 8;
  __bf16* lA1 = lA0 + 512;
  __bf16* lB0 = sB + wave * 1024 + lane * 8;
  __bf16* lB1 = lB0 + 512;

  f32x4 acc[4][4];
#pragma unroll
  for (int i = 0; i < 4; i++)
#pragma unroll
    for (int j = 0; j < 4; j++) acc[i][j] = (f32x4)0.0f;

  const int fr = lane & 15;
  const int kb = (lane >> 4) * 8;

  for (int kt = 0; kt < K; kt += 32) {
    __syncthreads();
    glds16(lA0, Ag + kt);
    glds16(lA1, Ag + (size_t)16 * K + kt);
    glds16(lB0, Bg + kt);
    glds16(lB1, Bg + (size_t)16 * K + kt);
    __syncthreads();
    bf16x8 af[4], bfr[4];
#pragma unroll
    for (int i = 0; i < 4; i++)
      af[i] = *(const bf16x8*)(sA + (wr * 64 + i * 16 + fr) * 32 + kb);
#pragma unroll
    for (int j = 0; j < 4; j++)
      bfr[j] = *(const bf16x8*)(sB + (wc * 64 + j * 16 + fr) * 32 + kb);
#pragma unroll
    for (int i = 0; i < 4; i++)
#pragma unroll
      for (int j = 0; j < 4; j++)
        acc[i][j] = MFMA_BF16(af[i], bfr[j], acc[i][j], 0, 0, 0);
  }

  const int rg = (lane >> 4) * 4;
#pragma unroll
  for (int i = 0; i < 4; i++)
#pragma unroll
    for (int j = 0; j < 4; j++) {
      size_t row = (size_t)bm * 128 + wr * 64 + i * 16 + rg;
      size_t col = (size_t)bn * 128 + wc * 64 + j * 16 + fr;
#pragma unroll
      for (int r = 0; r < 4; r++)
        Cout[(row + r) * N + col] = acc[i][j][r];
    }
}

// ---------------- stage A: G_c = K_c^T V_c per (b,h,chunk) ----------------
#define LDW 72
__global__ __launch_bounds__(256) void chunk_kv(const __bf16* __restrict__ qkv,
                                                __bf16* __restrict__ G) {
  __shared__ __bf16 Kt[64 * LDW];
  __shared__ __bf16 Vt[64 * LDW];
  const int bid = blockIdx.x;
  const int c = bid & (NC_ - 1);
  const int bh = bid >> 6;
  const int h = bh & (H_ - 1);
  const int b = bh >> 4;
  const int tid = threadIdx.x;
  const size_t row0 = (size_t)b * T_ + c * 64;
  const int kcol = C_ + h * 64;
  const int vcol = 2 * C_ + h * 64;
#pragma unroll
  for (int it = 0; it < 2; ++it) {
    int task = tid + it * 256;
    int t = task >> 3;
    int d0 = (task & 7) * 8;
    const size_t rb = (row0 + t) * N3_;
    u16x8 kv = *(const u16x8*)(qkv + rb + kcol + d0);
    u16x8 vv = *(const u16x8*)(qkv + rb + vcol + d0);
#pragma unroll
    for (int j = 0; j < 8; j++) {
      ((unsigned short*)Kt)[(d0 + j) * LDW + t] = kv[j];
      ((unsigned short*)Vt)[(d0 + j) * LDW + t] = vv[j];
    }
  }
  __syncthreads();
  const int lane = tid & 63, wave = tid >> 6;
  const int gr = (wave >> 1) * 32, gc = (wave & 1) * 32;
  const int fr = lane & 15, kb = (lane >> 4) * 8;
  f32x4 acc[2][2];
#pragma unroll
  for (int i = 0; i < 2; i++)
#pragma unroll
    for (int j = 0; j < 2; j++) acc[i][j] = (f32x4)0.0f;
#pragma unroll
  for (int kk = 0; kk < 2; ++kk) {
    bf16x8 af[2], bfr[2];
#pragma unroll
    for (int i = 0; i < 2; i++)
      af[i] = *(const bf16x8*)(Kt + (gr + i * 16 + fr) * LDW + kk * 32 + kb);
#pragma unroll
    for (int j = 0; j < 2; j++)
      bfr[j] = *(const bf16x8*)(Vt + (gc + j * 16 + fr) * LDW + kk * 32 + kb);
#pragma unroll
    for (int i = 0; i < 2; i++)
#pragma unroll
      for (int j = 0; j < 2; j++)
        acc[i][j] = MFMA_BF16(af[i], bfr[j], acc[i][j], 0, 0, 0);
  }
  const int rg = (lane >> 4) * 4;
  __bf16* Gb = G + (size_t)bid * 4096;
#pragma unroll
  for (int i = 0; i < 2; i++)
#pragma unroll
    for (int j = 0; j < 2; j++)
#pragma unroll
      for (int r = 0; r < 4; r++)
        Gb[(gr + i * 16 + rg + r) * 64 + gc + j * 16 + fr] = (__bf16)acc[i][j][r];
}

// ---------------- stage B: prefix over chunks ----------------
__global__ __launch_bounds__(256) void prefix_scan(const __bf16* __restrict__ G,
                                                   const float* __restrict__ sigma0,
                                                   __bf16* __restrict__ S,
                                                   float* __restrict__ sigma_out,
                                                   const float* __restrict__ eta) {
  const int blk = blockIdx.x;       // 0..255
  const int bh = blk >> 2;
  const int dq = blk & 3;
  const int tid = threadIdx.x;
  const int d = dq * 16 + (tid >> 4);
  const int e0 = (tid & 15) * 4;
  const float eta_s = eta[0];
  const size_t base_de = (size_t)d * 64 + e0;
  float acc[4], s0[4];
#pragma unroll
  for (int j = 0; j < 4; j++) {
    acc[j] = 0.0f;
    s0[j] = sigma0[(size_t)bh * 4096 + base_de + j];
  }
  for (int c = 0; c < NC_; ++c) {
    const size_t off = ((size_t)bh * NC_ + c) * 4096 + base_de;
    bf16x4 sv;
#pragma unroll
    for (int j = 0; j < 4; j++) sv[j] = (__bf16)(s0[j] + eta_s * acc[j]);
    *(bf16x4*)(S + off) = sv;
    bf16x4 g = *(const bf16x4*)(G + off);
#pragma unroll
    for (int j = 0; j < 4; j++) acc[j] += (float)g[j];
  }
  float4 v;
  v.x = s0[0] + eta_s * acc[0];
  v.y = s0[1] + eta_s * acc[1];
  v.z = s0[2] + eta_s * acc[2];
  v.w = s0[3] + eta_s * acc[3];
  *reinterpret_cast<float4*>(sigma_out + (size_t)bh * 4096 + base_de) = v;
}

// ---------------- stage C: O = eta*strict_tril(Q K^T) V + Q S_c ----------------
__global__ __launch_bounds__(256) void chunk_out(const __bf16* __restrict__ qkv,
                                                 const __bf16* __restrict__ S,
                                                 __bf16* __restrict__ outp,
                                                 const float* __restrict__ eta) {
  __shared__ __bf16 Qs[64 * LDW];
  __shared__ __bf16 Ks[64 * LDW];
  __shared__ __bf16 Vt[64 * LDW];
  __shared__ __bf16 St[64 * LDW];
  __shared__ __bf16 Ps[64 * LDW];
  const int bid = blockIdx.x;
  const int c = bid & 63, bh = bid >> 6, h = bh & 15, b = bh >> 4;
  const int tid = threadIdx.x;
  const size_t row0 = (size_t)b * T_ + c * 64;
  const float eta_s = eta[0];
#pragma unroll
  for (int it = 0; it < 2; ++it) {
    int task = tid + it * 256;
    int t = task >> 3, d0 = (task & 7) * 8;
    const size_t rb = (row0 + t) * N3_;
    *(u16x8*)(Qs + t * LDW + d0) = *(const u16x8*)(qkv + rb + h * 64 + d0);
    *(u16x8*)(Ks + t * LDW + d0) = *(const u16x8*)(qkv + rb + C_ + h * 64 + d0);
    u16x8 vv = *(const u16x8*)(qkv + rb + 2 * C_ + h * 64 + d0);
    u16x8 sv = *(const u16x8*)(S + (size_t)bid * 4096 + t * 64 + d0);
#pragma unroll
    for (int j = 0; j < 8; j++) {
      ((unsigned short*)Vt)[(d0 + j) * LDW + t] = vv[j];
      ((unsigned short*)St)[(d0 + j) * LDW + t] = sv[j];
    }
  }
  __syncthreads();
  const int lane = tid & 63, wave = tid >> 6;
  const int qr = (wave >> 1) * 32, qc = (wave & 1) * 32;
  const int fr = lane & 15, kb = (lane >> 4) * 8, rg = (lane >> 4) * 4;
  {
    f32x4 pacc[2][2];
#pragma unroll
    for (int i = 0; i < 2; i++)
#pragma unroll
      for (int j = 0; j < 2; j++) pacc[i][j] = (f32x4)0.0f;
#pragma unroll
    for (int kk = 0; kk < 2; ++kk) {
      bf16x8 af[2], bfr[2];
#pragma unroll
      for (int i = 0; i < 2; i++)
        af[i] = *(const bf16x8*)(Qs + (qr + i * 16 + fr) * LDW + kk * 32 + kb);
#pragma unroll
      for (int j = 0; j < 2; j++)
        bfr[j] = *(const bf16x8*)(Ks + (qc + j * 16 + fr) * LDW + kk * 32 + kb);
#pragma unroll
      for (int i = 0; i < 2; i++)
#pragma unroll
        for (int j = 0; j < 2; j++)
          pacc[i][j] = MFMA_BF16(af[i], bfr[j], pacc[i][j], 0, 0, 0);
    }
#pragma unroll
    for (int i = 0; i < 2; i++)
#pragma unroll
      for (int j = 0; j < 2; j++)
#pragma unroll
        for (int r = 0; r < 4; r++) {
          int trow = qr + i * 16 + rg + r;
          int scol = qc + j * 16 + fr;
          float v = (scol < trow) ? eta_s * pacc[i][j][r] : 0.0f;
          Ps[trow * LDW + scol] = (__bf16)v;
        }
  }
  __syncthreads();
  {
    f32x4 oacc[2][2];
#pragma unroll
    for (int i = 0; i < 2; i++)
#pragma unroll
      for (int j = 0; j < 2; j++) oacc[i][j] = (f32x4)0.0f;
#pragma unroll
    for (int kk = 0; kk < 2; ++kk) {
      bf16x8 pa[2], vb[2], qa[2], sb[2];
#pragma unroll
      for (int i = 0; i < 2; i++) {
        pa[i] = *(const bf16x8*)(Ps + (qr + i * 16 + fr) * LDW + kk * 32 + kb);
        qa[i] = *(const bf16x8*)(Qs + (qr + i * 16 + fr) * LDW + kk * 32 + kb);
      }
#pragma unroll
      for (int j = 0; j < 2; j++) {
        vb[j] = *(const bf16x8*)(Vt + (qc + j * 16 + fr) * LDW + kk * 32 + kb);
        sb[j] = *(const bf16x8*)(St + (qc + j * 16 + fr) * LDW + kk * 32 + kb);
      }
#pragma unroll
      for (int i = 0; i < 2; i++)
#pragma unroll
        for (int j = 0; j < 2; j++) {
          oacc[i][j] = MFMA_BF16(pa[i], vb[j], oacc[i][j], 0, 0, 0);
          oacc[i][j] = MFMA_BF16(qa[i], sb[j], oacc[i][j], 0, 0, 0);
        }
    }
#pragma unroll
    for (int i = 0; i < 2; i++)
#pragma unroll
      for (int j = 0; j < 2; j++)
#pragma unroll
        for (int r = 0; r < 4; r++) {
          size_t row = row0 + qr + i * 16 + rg + r;
          int col = h * 64 + qc + j * 16 + fr;
          outp[row * C_ + col] = (__bf16)oacc[i][j][r];
        }
  }
}

extern "C" void kernel_launch(void* const* d_in, const int* in_sizes, int n_in,
                              void* d_out, int out_size, void* d_ws, size_t ws_size,
                              hipStream_t stream) {
  const float* x      = (const float*)d_in[0];
  const float* sigma0 = (const float*)d_in[1];
  const float* w_qkv  = (const float*)d_in[2];
  const float* w_proj = (const float*)d_in[3];
  const float* eta    = (const float*)d_in[4];
  float* out       = (float*)d_out;
  float* sigma_out = out + (size_t)M_ * C_;

  char* ws = (char*)d_ws;
  __bf16* xbf     = (__bf16*)(ws);               // 32 MB (reused as out_pre)
  __bf16* wqkvbf  = (__bf16*)(ws + 33554432);
  __bf16* wprojbf = (__bf16*)(ws + 39845888);
  __bf16* qkvbf   = (__bf16*)(ws + 41943040);    // 96 MB
  __bf16* Gws     = (__bf16*)(ws + 142606336);   // 32 MB
  __bf16* Sws     = (__bf16*)(ws + 176160768);   // 32 MB
  float2* tab     = (float2*)(ws + 176160768);   // 1 MB, dead before prefix_scan writes S

  rope_tab<<<512, 256, 0, stream>>>(tab);
  cvt_f32_bf16<<<16384, 256, 0, stream>>>(x, xbf, 4194304);
  cvt_f32_bf16<<<3072, 256, 0, stream>>>(w_qkv, wqkvbf, 786432);
  cvt_f32_bf16<<<1024, 256, 0, stream>>>(w_proj, wprojbf, 262144);
  gemm1_pipe<<<dim3(24, 64), 512, 0, stream>>>(xbf, wqkvbf, qkvbf, tab);
  chunk_kv<<<4096, 256, 0, stream>>>(qkvbf, Gws);
  prefix_scan<<<256, 256, 0, stream>>>(Gws, sigma0, Sws, sigma_out, eta);
  chunk_out<<<4096, 256, 0, stream>>>(qkvbf, Sws, xbf, eta);
  gemm_bt_f32<<<dim3(8, 128), 256, 0, stream>>>(xbf, wprojbf, out, M_, C_, C_);
}